// Round 1
// baseline (38800.598 us; speedup 1.0000x reference)
//
#include <hip/hip_runtime.h>
#include <hip/hip_bf16.h>
#include <stdint.h>

#define LATENT 256
#define HIDDEN 1024
#define GOUT 512
#define NB 32
#define TT 512
#define G3 1536

typedef float f32x4 __attribute__((ext_vector_type(4)));
typedef short s16x8 __attribute__((ext_vector_type(8)));
typedef uint32_t u32;

#define GLP(p) ((const __attribute__((address_space(1))) u32*)(p))
#define LLP(p) ((__attribute__((address_space(3))) u32*)(p))

__device__ __forceinline__ short f2bf(float f) {
  u32 u = __builtin_bit_cast(u32, f);
  u32 r = (u + 0x7FFFu + ((u >> 16) & 1u)) >> 16;
  return (short)r;
}
__device__ __forceinline__ float bf2f(short s) {
  u32 u = ((u32)(unsigned short)s) << 16;
  return __builtin_bit_cast(float, u);
}
__device__ __forceinline__ u32 pk2(float a, float b) {
  return (u32)(unsigned short)f2bf(a) | ((u32)(unsigned short)f2bf(b) << 16);
}
__device__ __forceinline__ s16x8 f2bf8(float4 a, float4 b) {
  s16x8 r;
  r[0] = f2bf(a.x); r[1] = f2bf(a.y); r[2] = f2bf(a.z); r[3] = f2bf(a.w);
  r[4] = f2bf(b.x); r[5] = f2bf(b.y); r[6] = f2bf(b.z); r[7] = f2bf(b.w);
  return r;
}
__device__ __forceinline__ float ldgx(const float* p) { return *p; }
__device__ __forceinline__ float ldgx(const short* p) { return bf2f(*p); }

// ---------------- fc + relu:  hfc[32][1024] = relu(z @ fc_w^T + fc_b) ----------------
__global__ __launch_bounds__(256) void fc_kernel(const float* __restrict__ z,
                                                 const float* __restrict__ fc_w,
                                                 const float* __restrict__ fc_b,
                                                 float* __restrict__ hfc) {
  __shared__ float zs[LATENT];
  int tid = threadIdx.x;
  int gid = blockIdx.x * 256 + tid;
  int b = gid >> 10, j = gid & 1023;
  zs[tid] = z[b * LATENT + tid];   // b uniform per block (256 | 1024)
  __syncthreads();
  const float4* wr = (const float4*)(fc_w + (size_t)j * LATENT);
  float s = 0.f;
#pragma unroll
  for (int k = 0; k < LATENT / 4; ++k) {
    float4 wv = wr[k];
    float4 zv = *(const float4*)&zs[k * 4];
    s += wv.x * zv.x + wv.y * zv.y + wv.z * zv.z + wv.w * zv.w;
  }
  s += fc_b[j];
  hfc[gid] = fmaxf(s, 0.f);
}

// ------------- x0[t][b][k] = bf16(hfc[b][k] + chord[b][t][k]/100) -------------
__global__ __launch_bounds__(256) void x0_kernel(const float* __restrict__ hfc,
                                                 const float* __restrict__ chord,
                                                 short* __restrict__ x0) {
  int r = blockIdx.x;          // r = t*32 + b
  int b = r & 31, t = r >> 5;
  int k = threadIdx.x * 4;
  float4 c = *(const float4*)(chord + ((size_t)b * TT + t) * HIDDEN + k);
  float4 h = *(const float4*)(hfc + (size_t)b * HIDDEN + k);
  u32 p0 = pk2(h.x + c.x * 0.01f, h.y + c.y * 0.01f);
  u32 p1 = pk2(h.z + c.z * 0.01f, h.w + c.w * 0.01f);
  uint2 pv; pv.x = p0; pv.y = p1;
  *(uint2*)(x0 + (size_t)r * HIDDEN + k) = pv;
}

// ---------------- fp32 -> bf16 weight convert ----------------
__global__ __launch_bounds__(256) void cvt_kernel(const float* __restrict__ src,
                                                  short* __restrict__ dst, int n4) {
  int i = blockIdx.x * 256 + threadIdx.x;
  if (i < n4) {
    float4 v = ((const float4*)src)[i];
    uint2 pv; pv.x = pk2(v.x, v.y); pv.y = pk2(v.z, v.w);
    ((uint2*)dst)[i] = pv;
  }
}

// ---------------- GEMM: C[M][N] = A[M][K](bf16) @ Bw[N][K]^T(bf16), m97 recipe ----------------
template <typename OutT>
__global__ __launch_bounds__(256) void gemm_bt(const short* __restrict__ A,
                                               const short* __restrict__ Bw,
                                               OutT* __restrict__ C, int M, int N, int K) {
  __shared__ short As[128 * 32];
  __shared__ short Bs[128 * 32];
  const int tid = threadIdx.x;
  const int lane = tid & 63, wave = tid >> 6;
  const int l15 = lane & 15, quad = lane >> 4;
  const int n0 = blockIdx.x * 128, m0 = blockIdx.y * 128;
  const int wm = (wave >> 1) * 64, wn = (wave & 1) * 64;
  f32x4 acc[4][4] = {};
  for (int k0 = 0; k0 < K; k0 += 32) {
#pragma unroll
    for (int c = 0; c < 2; ++c) {
      int idx = c * 256 + tid;
      int row = idx >> 2, cs = (idx & 3) * 8;
      const u32* ga = (const u32*)(A + (size_t)(m0 + row) * K + k0 + cs);
      const u32* gb = (const u32*)(Bw + (size_t)(n0 + row) * K + k0 + cs);
      u32* sa = (u32*)As + (size_t)(c * 256 + wave * 64) * 4;
      u32* sb = (u32*)Bs + (size_t)(c * 256 + wave * 64) * 4;
      __builtin_amdgcn_global_load_lds(GLP(ga), LLP(sa), 16, 0, 0);
      __builtin_amdgcn_global_load_lds(GLP(gb), LLP(sb), 16, 0, 0);
    }
    __syncthreads();
    s16x8 af[4], bfr[4];
#pragma unroll
    for (int i = 0; i < 4; ++i)
      af[i] = *(const s16x8*)(As + (wm + i * 16 + l15) * 32 + quad * 8);
#pragma unroll
    for (int j = 0; j < 4; ++j)
      bfr[j] = *(const s16x8*)(Bs + (wn + j * 16 + l15) * 32 + quad * 8);
#pragma unroll
    for (int i = 0; i < 4; ++i)
#pragma unroll
      for (int j = 0; j < 4; ++j)
        acc[i][j] = __builtin_amdgcn_mfma_f32_16x16x32_bf16(af[i], bfr[j], acc[i][j], 0, 0, 0);
    __syncthreads();
  }
#pragma unroll
  for (int i = 0; i < 4; ++i)
#pragma unroll
    for (int j = 0; j < 4; ++j)
#pragma unroll
      for (int r = 0; r < 4; ++r) {
        int m = m0 + wm + i * 16 + quad * 4 + r;
        int n = n0 + wn + j * 16 + l15;
        float v = acc[i][j][r];
        if constexpr (__is_same(OutT, float)) C[(size_t)m * N + n] = v;
        else C[(size_t)m * N + n] = f2bf(v);
      }
}

// ---------------- persistent GRU layer ----------------
// 8 independent batch-groups (4 batches each) x 16 WGs (32 hidden units each).
// Per WG: 6 waves = (gate r/z/n) x (unit half). w_hh B-frags live in VGPRs.
template <typename GxT>
__global__ __launch_bounds__(384) void gru_layer(const GxT* __restrict__ gx,       // [T][32][1536]
                                                 const float* __restrict__ w_hh,   // [1536][512]
                                                 const float* __restrict__ b_ih,
                                                 const float* __restrict__ b_hh,
                                                 short* __restrict__ h_buf,        // [2][8][4][512] bf16
                                                 int* cnt,                         // group counters, 64B apart
                                                 short* __restrict__ x_out,        // [T][32][512] bf16 or null
                                                 float* __restrict__ f_out,        // [32][T][512] fp32 or null
                                                 const int* __restrict__ seq_lens) {
  const int bid = blockIdx.x;
  const int g = bid & 7, wg = bid >> 3;
  const int tid = threadIdx.x, lane = tid & 63, wave = tid >> 6;
  const int l15 = lane & 15, quad = lane >> 4;
  const int gate = wave >> 1, half = wave & 1;
  const int ub = wg * 32 + half * 16;
  const int col = gate * 512 + ub + l15;     // w_hh row this lane covers
  __shared__ float lds_gh[4][4][16];         // [(gate-1)*2+half][batch][unit]

  // --- persistent weight fragments (bf16, 64 VGPRs) ---
  s16x8 wfrag[16];
#pragma unroll
  for (int kb = 0; kb < 16; ++kb) {
    const float* p = w_hh + (size_t)col * 512 + kb * 32 + quad * 8;
    wfrag[kb] = f2bf8(*(const float4*)p, *(const float4*)(p + 4));
  }

  const int u = ub + l15;
  float bihr = 0, bihz = 0, bihn = 0, bhhr = 0, bhhz = 0, bhhn = 0;
  if (gate == 0) {
    bihr = b_ih[u]; bihz = b_ih[512 + u]; bihn = b_ih[1024 + u];
    bhhr = b_hh[u]; bhhz = b_hh[512 + u]; bhhn = b_hh[1024 + u];
  }
  int slen[4];
#pragma unroll
  for (int r = 0; r < 4; ++r) slen[r] = seq_lens[g * 4 + r];

  float hprev[4] = {0.f, 0.f, 0.f, 0.f};
  float pgx[3][4];
  if (gate == 0 && quad == 0) {
#pragma unroll
    for (int gt = 0; gt < 3; ++gt)
#pragma unroll
      for (int r = 0; r < 4; ++r)
        pgx[gt][r] = ldgx(&gx[(size_t)(g * 4 + r) * G3 + gt * 512 + u]);
  }
  int* c = cnt + g * 16;

  for (int t = 0; t < TT; ++t) {
    f32x4 acc = {0.f, 0.f, 0.f, 0.f};
    float cur[3][4];
    if (gate == 0 && quad == 0) {
#pragma unroll
      for (int gt = 0; gt < 3; ++gt)
#pragma unroll
        for (int r = 0; r < 4; ++r) cur[gt][r] = pgx[gt][r];
      if (t + 1 < TT) {
#pragma unroll
        for (int gt = 0; gt < 3; ++gt)
#pragma unroll
          for (int r = 0; r < 4; ++r)
            pgx[gt][r] = ldgx(&gx[(size_t)((t + 1) * NB + g * 4 + r) * G3 + gt * 512 + u]);
      }
    }
    if (t > 0) {
      const short* hb = h_buf + (size_t)((((t - 1) & 1) * 8 + g) * 4 + (l15 & 3)) * 512;
#pragma unroll
      for (int kb = 0; kb < 16; ++kb) {
        s16x8 a = *(const s16x8*)(hb + kb * 32 + quad * 8);
        acc = __builtin_amdgcn_mfma_f32_16x16x32_bf16(a, wfrag[kb], acc, 0, 0, 0);
      }
    }
    if (gate > 0 && quad == 0) {
#pragma unroll
      for (int r = 0; r < 4; ++r) lds_gh[(gate - 1) * 2 + half][r][l15] = acc[r];
    }
    __syncthreads();
    if (gate == 0) {
      if (quad == 0) {
#pragma unroll
        for (int r = 0; r < 4; ++r) {
          float ghr = acc[r];
          float ghz = lds_gh[half][r][l15];
          float ghn = lds_gh[2 + half][r][l15];
          float xr = cur[0][r] + bihr + ghr + bhhr;
          float xz = cur[1][r] + bihz + ghz + bhhz;
          float rr = 1.f / (1.f + __expf(-xr));
          float zz = 1.f / (1.f + __expf(-xz));
          float pre = cur[2][r] + bihn + rr * (ghn + bhhn);
          float ax = fabsf(pre);
          float e = __expf(-2.f * ax);
          float nn = copysignf((1.f - e) / (1.f + e), pre);
          float h = (1.f - zz) * nn + zz * hprev[r];
          hprev[r] = h;
          float other = __shfl_xor(h, 1);
          if ((lane & 1) == 0) {
            u32 pk = pk2(h, other);
            u32* dst = (u32*)(h_buf + (size_t)(((t & 1) * 8 + g) * 4 + r) * 512 + u);
            __hip_atomic_store(dst, pk, __ATOMIC_RELAXED, __HIP_MEMORY_SCOPE_AGENT);
          }
          if (x_out) x_out[(size_t)(t * NB + g * 4 + r) * 512 + u] = f2bf(h);
          if (f_out) f_out[((size_t)(g * 4 + r) * TT + t) * 512 + u] = (t < slen[r]) ? h : 0.f;
        }
      }
      if (lane == 0 && t + 1 < TT)
        __hip_atomic_fetch_add(c, 1, __ATOMIC_RELEASE, __HIP_MEMORY_SCOPE_AGENT);
    }
    if (t + 1 < TT) {
      int target = (t + 1) * 32;   // 16 WGs x 2 arriving waves
      while (__hip_atomic_load(c, __ATOMIC_ACQUIRE, __HIP_MEMORY_SCOPE_AGENT) < target)
        __builtin_amdgcn_s_sleep(1);
    }
  }
}

extern "C" void kernel_launch(void* const* d_in, const int* in_sizes, int n_in,
                              void* d_out, int out_size, void* d_ws, size_t ws_size,
                              hipStream_t stream) {
  (void)in_sizes; (void)n_in; (void)out_size;
  const float* z       = (const float*)d_in[0];
  const int*   seq     = (const int*)d_in[1];
  const float* chord   = (const float*)d_in[2];
  const float* fc_w    = (const float*)d_in[3];
  const float* fc_b    = (const float*)d_in[4];
  const float* w_ih[3] = {(const float*)d_in[5], (const float*)d_in[9],  (const float*)d_in[13]};
  const float* w_hh[3] = {(const float*)d_in[6], (const float*)d_in[10], (const float*)d_in[14]};
  const float* b_ih[3] = {(const float*)d_in[7], (const float*)d_in[11], (const float*)d_in[15]};
  const float* b_hh[3] = {(const float*)d_in[8], (const float*)d_in[12], (const float*)d_in[16]};

  char* w = (char*)d_ws;
  size_t off = 0;
  auto alloc = [&](size_t bytes) -> void* {
    void* p = w + off;
    off = (off + bytes + 255) & ~(size_t)255;
    return p;
  };
  int*   cnt  = (int*)alloc(4096);
  short* hbuf = (short*)alloc((size_t)2 * 8 * 4 * 512 * 2);
  float* hfc  = (float*)alloc((size_t)NB * HIDDEN * 4);
  short* x0   = (short*)alloc((size_t)TT * NB * HIDDEN * 2);
  short* x1   = (short*)alloc((size_t)TT * NB * GOUT * 2);   // reused as x2
  short* w0b  = (short*)alloc((size_t)G3 * HIDDEN * 2);
  short* w1b  = (short*)alloc((size_t)G3 * GOUT * 2);
  short* w2b  = (short*)alloc((size_t)G3 * GOUT * 2);
  size_t fixed = off;
  bool gx_f32 = (fixed + (size_t)TT * NB * G3 * 4) <= ws_size;
  void* gx = alloc(gx_f32 ? (size_t)TT * NB * G3 * 4 : (size_t)TT * NB * G3 * 2);

  hipMemsetAsync(cnt, 0, 4096, stream);
  fc_kernel<<<128, 256, 0, stream>>>(z, fc_w, fc_b, hfc);
  x0_kernel<<<TT * NB, 256, 0, stream>>>(hfc, chord, x0);
  cvt_kernel<<<(G3 * HIDDEN / 4 + 255) / 256, 256, 0, stream>>>(w_ih[0], w0b, G3 * HIDDEN / 4);
  cvt_kernel<<<(G3 * GOUT / 4 + 255) / 256, 256, 0, stream>>>(w_ih[1], w1b, G3 * GOUT / 4);
  cvt_kernel<<<(G3 * GOUT / 4 + 255) / 256, 256, 0, stream>>>(w_ih[2], w2b, G3 * GOUT / 4);

  dim3 gg(G3 / 128, TT * NB / 128);
  if (gx_f32) {
    float* gxf = (float*)gx;
    gemm_bt<float><<<gg, 256, 0, stream>>>(x0, w0b, gxf, TT * NB, G3, HIDDEN);
    gru_layer<float><<<128, 384, 0, stream>>>(gxf, w_hh[0], b_ih[0], b_hh[0], hbuf, cnt + 0,   x1, nullptr, seq);
    gemm_bt<float><<<gg, 256, 0, stream>>>(x1, w1b, gxf, TT * NB, G3, GOUT);
    gru_layer<float><<<128, 384, 0, stream>>>(gxf, w_hh[1], b_ih[1], b_hh[1], hbuf, cnt + 128, x1, nullptr, seq);
    gemm_bt<float><<<gg, 256, 0, stream>>>(x1, w2b, gxf, TT * NB, G3, GOUT);
    gru_layer<float><<<128, 384, 0, stream>>>(gxf, w_hh[2], b_ih[2], b_hh[2], hbuf, cnt + 256, nullptr, (float*)d_out, seq);
  } else {
    short* gxb = (short*)gx;
    gemm_bt<short><<<gg, 256, 0, stream>>>(x0, w0b, gxb, TT * NB, G3, HIDDEN);
    gru_layer<short><<<128, 384, 0, stream>>>(gxb, w_hh[0], b_ih[0], b_hh[0], hbuf, cnt + 0,   x1, nullptr, seq);
    gemm_bt<short><<<gg, 256, 0, stream>>>(x1, w1b, gxb, TT * NB, G3, GOUT);
    gru_layer<short><<<128, 384, 0, stream>>>(gxb, w_hh[1], b_ih[1], b_hh[1], hbuf, cnt + 128, x1, nullptr, seq);
    gemm_bt<short><<<gg, 256, 0, stream>>>(x1, w2b, gxb, TT * NB, G3, GOUT);
    gru_layer<short><<<128, 384, 0, stream>>>(gxb, w_hh[2], b_ih[2], b_hh[2], hbuf, cnt + 256, nullptr, (float*)d_out, seq);
  }
}

// Round 2
// 12989.110 us; speedup vs baseline: 2.9872x; 2.9872x over previous
//
#include <hip/hip_runtime.h>
#include <hip/hip_bf16.h>
#include <stdint.h>

#define LATENT 256
#define HIDDEN 1024
#define GOUT 512
#define NB 32
#define TT 512
#define G3 1536

typedef float f32x4 __attribute__((ext_vector_type(4)));
typedef short s16x8 __attribute__((ext_vector_type(8)));
typedef uint32_t u32;

#define GLP(p) ((const __attribute__((address_space(1))) u32*)(p))
#define LLP(p) ((__attribute__((address_space(3))) u32*)(p))

__device__ __forceinline__ short f2bf(float f) {
  u32 u = __builtin_bit_cast(u32, f);
  u32 r = (u + 0x7FFFu + ((u >> 16) & 1u)) >> 16;
  return (short)r;
}
__device__ __forceinline__ float bf2f(short s) {
  u32 u = ((u32)(unsigned short)s) << 16;
  return __builtin_bit_cast(float, u);
}
__device__ __forceinline__ u32 pk2(float a, float b) {
  return (u32)(unsigned short)f2bf(a) | ((u32)(unsigned short)f2bf(b) << 16);
}
__device__ __forceinline__ s16x8 f2bf8(float4 a, float4 b) {
  s16x8 r;
  r[0] = f2bf(a.x); r[1] = f2bf(a.y); r[2] = f2bf(a.z); r[3] = f2bf(a.w);
  r[4] = f2bf(b.x); r[5] = f2bf(b.y); r[6] = f2bf(b.z); r[7] = f2bf(b.w);
  return r;
}
__device__ __forceinline__ float ldgx(const float* p) { return *p; }
__device__ __forceinline__ float ldgx(const short* p) { return bf2f(*p); }

// ---------------- fc + relu:  hfc[32][1024] = relu(z @ fc_w^T + fc_b) ----------------
__global__ __launch_bounds__(256) void fc_kernel(const float* __restrict__ z,
                                                 const float* __restrict__ fc_w,
                                                 const float* __restrict__ fc_b,
                                                 float* __restrict__ hfc) {
  __shared__ float zs[LATENT];
  int tid = threadIdx.x;
  int gid = blockIdx.x * 256 + tid;
  int b = gid >> 10, j = gid & 1023;
  zs[tid] = z[b * LATENT + tid];   // b uniform per block (256 | 1024)
  __syncthreads();
  const float4* wr = (const float4*)(fc_w + (size_t)j * LATENT);
  float s = 0.f;
#pragma unroll
  for (int k = 0; k < LATENT / 4; ++k) {
    float4 wv = wr[k];
    float4 zv = *(const float4*)&zs[k * 4];
    s += wv.x * zv.x + wv.y * zv.y + wv.z * zv.z + wv.w * zv.w;
  }
  s += fc_b[j];
  hfc[gid] = fmaxf(s, 0.f);
}

// ------------- x0[t][b][k] = bf16(hfc[b][k] + chord[b][t][k]/100) -------------
__global__ __launch_bounds__(256) void x0_kernel(const float* __restrict__ hfc,
                                                 const float* __restrict__ chord,
                                                 short* __restrict__ x0) {
  int r = blockIdx.x;          // r = t*32 + b
  int b = r & 31, t = r >> 5;
  int k = threadIdx.x * 4;
  float4 c = *(const float4*)(chord + ((size_t)b * TT + t) * HIDDEN + k);
  float4 h = *(const float4*)(hfc + (size_t)b * HIDDEN + k);
  u32 p0 = pk2(h.x + c.x * 0.01f, h.y + c.y * 0.01f);
  u32 p1 = pk2(h.z + c.z * 0.01f, h.w + c.w * 0.01f);
  uint2 pv; pv.x = p0; pv.y = p1;
  *(uint2*)(x0 + (size_t)r * HIDDEN + k) = pv;
}

// ---------------- fp32 -> bf16 weight convert ----------------
__global__ __launch_bounds__(256) void cvt_kernel(const float* __restrict__ src,
                                                  short* __restrict__ dst, int n4) {
  int i = blockIdx.x * 256 + threadIdx.x;
  if (i < n4) {
    float4 v = ((const float4*)src)[i];
    uint2 pv; pv.x = pk2(v.x, v.y); pv.y = pk2(v.z, v.w);
    ((uint2*)dst)[i] = pv;
  }
}

// ---------------- GEMM: C[M][N] = A[M][K](bf16) @ Bw[N][K]^T(bf16), m97 recipe ----------------
template <typename OutT>
__global__ __launch_bounds__(256) void gemm_bt(const short* __restrict__ A,
                                               const short* __restrict__ Bw,
                                               OutT* __restrict__ C, int M, int N, int K) {
  __shared__ short As[128 * 32];
  __shared__ short Bs[128 * 32];
  const int tid = threadIdx.x;
  const int lane = tid & 63, wave = tid >> 6;
  const int l15 = lane & 15, quad = lane >> 4;
  const int n0 = blockIdx.x * 128, m0 = blockIdx.y * 128;
  const int wm = (wave >> 1) * 64, wn = (wave & 1) * 64;
  f32x4 acc[4][4] = {};
  for (int k0 = 0; k0 < K; k0 += 32) {
#pragma unroll
    for (int c = 0; c < 2; ++c) {
      int idx = c * 256 + tid;
      int row = idx >> 2, cs = (idx & 3) * 8;
      const u32* ga = (const u32*)(A + (size_t)(m0 + row) * K + k0 + cs);
      const u32* gb = (const u32*)(Bw + (size_t)(n0 + row) * K + k0 + cs);
      u32* sa = (u32*)As + (size_t)(c * 256 + wave * 64) * 4;
      u32* sb = (u32*)Bs + (size_t)(c * 256 + wave * 64) * 4;
      __builtin_amdgcn_global_load_lds(GLP(ga), LLP(sa), 16, 0, 0);
      __builtin_amdgcn_global_load_lds(GLP(gb), LLP(sb), 16, 0, 0);
    }
    __syncthreads();
    s16x8 af[4], bfr[4];
#pragma unroll
    for (int i = 0; i < 4; ++i)
      af[i] = *(const s16x8*)(As + (wm + i * 16 + l15) * 32 + quad * 8);
#pragma unroll
    for (int j = 0; j < 4; ++j)
      bfr[j] = *(const s16x8*)(Bs + (wn + j * 16 + l15) * 32 + quad * 8);
#pragma unroll
    for (int i = 0; i < 4; ++i)
#pragma unroll
      for (int j = 0; j < 4; ++j)
        acc[i][j] = __builtin_amdgcn_mfma_f32_16x16x32_bf16(af[i], bfr[j], acc[i][j], 0, 0, 0);
    __syncthreads();
  }
#pragma unroll
  for (int i = 0; i < 4; ++i)
#pragma unroll
    for (int j = 0; j < 4; ++j)
#pragma unroll
      for (int r = 0; r < 4; ++r) {
        int m = m0 + wm + i * 16 + quad * 4 + r;
        int n = n0 + wn + j * 16 + l15;
        float v = acc[i][j][r];
        if constexpr (__is_same(OutT, float)) C[(size_t)m * N + n] = v;
        else C[(size_t)m * N + n] = f2bf(v);
      }
}

// ---------------- persistent GRU layer ----------------
// 8 independent batch-groups (4 batches each) x 16 WGs (32 hidden units each).
// Per WG: 6 waves = (gate r/z/n) x (unit half). w_hh B-frags live in VGPRs.
// Per-step sync: flag-per-producing-wave (padded, store-release), wave0-only
// relaxed polling + single acquire fence, syncthreads broadcast. No RMW, no
// per-iteration buffer_inv.
template <typename GxT>
__global__ __launch_bounds__(384) void gru_layer(const GxT* __restrict__ gx,       // [T][32][1536]
                                                 const float* __restrict__ w_hh,   // [1536][512]
                                                 const float* __restrict__ b_ih,
                                                 const float* __restrict__ b_hh,
                                                 short* __restrict__ h_buf,        // [2][8][4][512] bf16
                                                 int* flags,                        // [8][32][16] ints, zeroed
                                                 short* __restrict__ x_out,        // [T][32][512] bf16 or null
                                                 float* __restrict__ f_out,        // [32][T][512] fp32 or null
                                                 const int* __restrict__ seq_lens) {
  const int bid = blockIdx.x;
  const int g = bid & 7, wg = bid >> 3;
  const int tid = threadIdx.x, lane = tid & 63, wave = tid >> 6;
  const int l15 = lane & 15, quad = lane >> 4;
  const int gate = wave >> 1, half = wave & 1;
  const int ub = wg * 32 + half * 16;
  const int col = gate * 512 + ub + l15;     // w_hh row this lane covers
  __shared__ float lds_gh[4][4][16];         // [(gate-1)*2+half][batch][unit]

  int* fgrp = flags + g * 32 * 16;           // this group's 32 flags, 64B apart

  // --- persistent weight fragments (bf16, 64 VGPRs) ---
  s16x8 wfrag[16];
#pragma unroll
  for (int kb = 0; kb < 16; ++kb) {
    const float* p = w_hh + (size_t)col * 512 + kb * 32 + quad * 8;
    wfrag[kb] = f2bf8(*(const float4*)p, *(const float4*)(p + 4));
  }

  const int u = ub + l15;
  float bihr = 0, bihz = 0, bihn = 0, bhhr = 0, bhhz = 0, bhhn = 0;
  if (gate == 0) {
    bihr = b_ih[u]; bihz = b_ih[512 + u]; bihn = b_ih[1024 + u];
    bhhr = b_hh[u]; bhhz = b_hh[512 + u]; bhhn = b_hh[1024 + u];
  }
  int slen[4];
#pragma unroll
  for (int r = 0; r < 4; ++r) slen[r] = seq_lens[g * 4 + r];

  float hprev[4] = {0.f, 0.f, 0.f, 0.f};
  float pgx[3][4];
  if (gate == 0 && quad == 0) {
#pragma unroll
    for (int gt = 0; gt < 3; ++gt)
#pragma unroll
      for (int r = 0; r < 4; ++r)
        pgx[gt][r] = ldgx(&gx[(size_t)(g * 4 + r) * G3 + gt * 512 + u]);
  }

  for (int t = 0; t < TT; ++t) {
    // ---- wait until all 32 producing waves of this group flagged step t ----
    if (t > 0) {
      if (wave == 0) {
        for (;;) {
          int v = 0;
          if (lane < 32)
            v = __hip_atomic_load(fgrp + lane * 16, __ATOMIC_RELAXED, __HIP_MEMORY_SCOPE_AGENT);
          unsigned long long rdy = __ballot(v >= t);
          if ((rdy & 0xFFFFFFFFull) == 0xFFFFFFFFull) break;
          __builtin_amdgcn_s_sleep(1);
        }
        __builtin_amdgcn_fence(__ATOMIC_ACQUIRE, "agent");
      }
      __syncthreads();
    }

    f32x4 acc = {0.f, 0.f, 0.f, 0.f};
    float cur[3][4];
    if (gate == 0 && quad == 0) {
#pragma unroll
      for (int gt = 0; gt < 3; ++gt)
#pragma unroll
        for (int r = 0; r < 4; ++r) cur[gt][r] = pgx[gt][r];
      if (t + 1 < TT) {
#pragma unroll
        for (int gt = 0; gt < 3; ++gt)
#pragma unroll
          for (int r = 0; r < 4; ++r)
            pgx[gt][r] = ldgx(&gx[(size_t)((t + 1) * NB + g * 4 + r) * G3 + gt * 512 + u]);
      }
    }
    if (t > 0) {
      const short* hb = h_buf + (size_t)((((t - 1) & 1) * 8 + g) * 4 + (l15 & 3)) * 512;
#pragma unroll
      for (int kb = 0; kb < 16; ++kb) {
        s16x8 a = *(const s16x8*)(hb + kb * 32 + quad * 8);
        acc = __builtin_amdgcn_mfma_f32_16x16x32_bf16(a, wfrag[kb], acc, 0, 0, 0);
      }
    }
    if (gate > 0 && quad == 0) {
#pragma unroll
      for (int r = 0; r < 4; ++r) lds_gh[(gate - 1) * 2 + half][r][l15] = acc[r];
    }
    __syncthreads();
    if (gate == 0) {
      if (quad == 0) {
#pragma unroll
        for (int r = 0; r < 4; ++r) {
          float ghr = acc[r];
          float ghz = lds_gh[half][r][l15];
          float ghn = lds_gh[2 + half][r][l15];
          float xr = cur[0][r] + bihr + ghr + bhhr;
          float xz = cur[1][r] + bihz + ghz + bhhz;
          float rr = 1.f / (1.f + __expf(-xr));
          float zz = 1.f / (1.f + __expf(-xz));
          float pre = cur[2][r] + bihn + rr * (ghn + bhhn);
          float ax = fabsf(pre);
          float e = __expf(-2.f * ax);
          float nn = copysignf((1.f - e) / (1.f + e), pre);
          float h = (1.f - zz) * nn + zz * hprev[r];
          hprev[r] = h;
          float other = __shfl_xor(h, 1);
          if ((lane & 1) == 0) {
            u32 pk = pk2(h, other);
            u32* dst = (u32*)(h_buf + (size_t)(((t & 1) * 8 + g) * 4 + r) * 512 + u);
            __hip_atomic_store(dst, pk, __ATOMIC_RELAXED, __HIP_MEMORY_SCOPE_AGENT);
          }
          if (x_out) x_out[(size_t)(t * NB + g * 4 + r) * 512 + u] = f2bf(h);
          if (f_out) f_out[((size_t)(g * 4 + r) * TT + t) * 512 + u] = (t < slen[r]) ? h : 0.f;
        }
      }
      if (t + 1 < TT) {
        // drain this wave's h stores to the coherence point, then flag.
        __builtin_amdgcn_fence(__ATOMIC_RELEASE, "agent");
        if (lane == 0)
          __hip_atomic_store(fgrp + (wg * 2 + half) * 16, t + 1,
                             __ATOMIC_RELAXED, __HIP_MEMORY_SCOPE_AGENT);
      }
    }
  }
}

extern "C" void kernel_launch(void* const* d_in, const int* in_sizes, int n_in,
                              void* d_out, int out_size, void* d_ws, size_t ws_size,
                              hipStream_t stream) {
  (void)in_sizes; (void)n_in; (void)out_size;
  const float* z       = (const float*)d_in[0];
  const int*   seq     = (const int*)d_in[1];
  const float* chord   = (const float*)d_in[2];
  const float* fc_w    = (const float*)d_in[3];
  const float* fc_b    = (const float*)d_in[4];
  const float* w_ih[3] = {(const float*)d_in[5], (const float*)d_in[9],  (const float*)d_in[13]};
  const float* w_hh[3] = {(const float*)d_in[6], (const float*)d_in[10], (const float*)d_in[14]};
  const float* b_ih[3] = {(const float*)d_in[7], (const float*)d_in[11], (const float*)d_in[15]};
  const float* b_hh[3] = {(const float*)d_in[8], (const float*)d_in[12], (const float*)d_in[16]};

  char* w = (char*)d_ws;
  size_t off = 0;
  auto alloc = [&](size_t bytes) -> void* {
    void* p = w + off;
    off = (off + bytes + 255) & ~(size_t)255;
    return p;
  };
  // flags: 3 layers x 8 groups x 32 flags x 16 ints (64B padded)
  int*   flags = (int*)alloc(3 * 8 * 32 * 16 * 4);
  short* hbuf = (short*)alloc((size_t)2 * 8 * 4 * 512 * 2);
  float* hfc  = (float*)alloc((size_t)NB * HIDDEN * 4);
  short* x0   = (short*)alloc((size_t)TT * NB * HIDDEN * 2);
  short* x1   = (short*)alloc((size_t)TT * NB * GOUT * 2);   // reused as x2
  short* w0b  = (short*)alloc((size_t)G3 * HIDDEN * 2);
  short* w1b  = (short*)alloc((size_t)G3 * GOUT * 2);
  short* w2b  = (short*)alloc((size_t)G3 * GOUT * 2);
  size_t fixed = off;
  bool gx_f32 = (fixed + (size_t)TT * NB * G3 * 4) <= ws_size;
  void* gx = alloc(gx_f32 ? (size_t)TT * NB * G3 * 4 : (size_t)TT * NB * G3 * 2);
  const int FL = 8 * 32 * 16;   // ints per layer's flag region

  hipMemsetAsync(flags, 0, 3 * FL * 4, stream);
  fc_kernel<<<128, 256, 0, stream>>>(z, fc_w, fc_b, hfc);
  x0_kernel<<<TT * NB, 256, 0, stream>>>(hfc, chord, x0);
  cvt_kernel<<<(G3 * HIDDEN / 4 + 255) / 256, 256, 0, stream>>>(w_ih[0], w0b, G3 * HIDDEN / 4);
  cvt_kernel<<<(G3 * GOUT / 4 + 255) / 256, 256, 0, stream>>>(w_ih[1], w1b, G3 * GOUT / 4);
  cvt_kernel<<<(G3 * GOUT / 4 + 255) / 256, 256, 0, stream>>>(w_ih[2], w2b, G3 * GOUT / 4);

  dim3 gg(G3 / 128, TT * NB / 128);
  if (gx_f32) {
    float* gxf = (float*)gx;
    gemm_bt<float><<<gg, 256, 0, stream>>>(x0, w0b, gxf, TT * NB, G3, HIDDEN);
    gru_layer<float><<<128, 384, 0, stream>>>(gxf, w_hh[0], b_ih[0], b_hh[0], hbuf, flags + 0 * FL, x1, nullptr, seq);
    gemm_bt<float><<<gg, 256, 0, stream>>>(x1, w1b, gxf, TT * NB, G3, GOUT);
    gru_layer<float><<<128, 384, 0, stream>>>(gxf, w_hh[1], b_ih[1], b_hh[1], hbuf, flags + 1 * FL, x1, nullptr, seq);
    gemm_bt<float><<<gg, 256, 0, stream>>>(x1, w2b, gxf, TT * NB, G3, GOUT);
    gru_layer<float><<<128, 384, 0, stream>>>(gxf, w_hh[2], b_ih[2], b_hh[2], hbuf, flags + 2 * FL, nullptr, (float*)d_out, seq);
  } else {
    short* gxb = (short*)gx;
    gemm_bt<short><<<gg, 256, 0, stream>>>(x0, w0b, gxb, TT * NB, G3, HIDDEN);
    gru_layer<short><<<128, 384, 0, stream>>>(gxb, w_hh[0], b_ih[0], b_hh[0], hbuf, flags + 0 * FL, x1, nullptr, seq);
    gemm_bt<short><<<gg, 256, 0, stream>>>(x1, w1b, gxb, TT * NB, G3, GOUT);
    gru_layer<short><<<gg.x * 0 + 128, 384, 0, stream>>>(gxb, w_hh[1], b_ih[1], b_hh[1], hbuf, flags + 1 * FL, x1, nullptr, seq);
    gemm_bt<short><<<gg, 256, 0, stream>>>(x1, w2b, gxb, TT * NB, G3, GOUT);
    gru_layer<short><<<128, 384, 0, stream>>>(gxb, w_hh[2], b_ih[2], b_hh[2], hbuf, flags + 2 * FL, nullptr, (float*)d_out, seq);
  }
}

// Round 3
// 4198.783 us; speedup vs baseline: 9.2409x; 3.0935x over previous
//
#include <hip/hip_runtime.h>
#include <hip/hip_bf16.h>
#include <stdint.h>

#define LATENT 256
#define HIDDEN 1024
#define GOUT 512
#define NB 32
#define TT 512
#define G3 1536

typedef float f32x4 __attribute__((ext_vector_type(4)));
typedef short s16x8 __attribute__((ext_vector_type(8)));
typedef uint32_t u32;
typedef unsigned long long u64;

#define GLP(p) ((const __attribute__((address_space(1))) u32*)(p))
#define LLP(p) ((__attribute__((address_space(3))) u32*)(p))

__device__ __forceinline__ short f2bf(float f) {
  u32 u = __builtin_bit_cast(u32, f);
  u32 r = (u + 0x7FFFu + ((u >> 16) & 1u)) >> 16;
  return (short)r;
}
__device__ __forceinline__ float bf2f(short s) {
  u32 u = ((u32)(unsigned short)s) << 16;
  return __builtin_bit_cast(float, u);
}
__device__ __forceinline__ u32 pk2(float a, float b) {
  return (u32)(unsigned short)f2bf(a) | ((u32)(unsigned short)f2bf(b) << 16);
}
__device__ __forceinline__ s16x8 f2bf8(float4 a, float4 b) {
  s16x8 r;
  r[0] = f2bf(a.x); r[1] = f2bf(a.y); r[2] = f2bf(a.z); r[3] = f2bf(a.w);
  r[4] = f2bf(b.x); r[5] = f2bf(b.y); r[6] = f2bf(b.z); r[7] = f2bf(b.w);
  return r;
}
__device__ __forceinline__ float ldgx(const float* p) { return *p; }
__device__ __forceinline__ float ldgx(const short* p) { return bf2f(*p); }

// ---------------- fc + relu:  hfc[32][1024] = relu(z @ fc_w^T + fc_b) ----------------
__global__ __launch_bounds__(256) void fc_kernel(const float* __restrict__ z,
                                                 const float* __restrict__ fc_w,
                                                 const float* __restrict__ fc_b,
                                                 float* __restrict__ hfc) {
  __shared__ float zs[LATENT];
  int tid = threadIdx.x;
  int gid = blockIdx.x * 256 + tid;
  int b = gid >> 10, j = gid & 1023;
  zs[tid] = z[b * LATENT + tid];
  __syncthreads();
  const float4* wr = (const float4*)(fc_w + (size_t)j * LATENT);
  float s = 0.f;
#pragma unroll
  for (int k = 0; k < LATENT / 4; ++k) {
    float4 wv = wr[k];
    float4 zv = *(const float4*)&zs[k * 4];
    s += wv.x * zv.x + wv.y * zv.y + wv.z * zv.z + wv.w * zv.w;
  }
  s += fc_b[j];
  hfc[gid] = fmaxf(s, 0.f);
}

// ------------- x0[t][b][k] = bf16(hfc[b][k] + chord[b][t][k]/100) -------------
__global__ __launch_bounds__(256) void x0_kernel(const float* __restrict__ hfc,
                                                 const float* __restrict__ chord,
                                                 short* __restrict__ x0) {
  int r = blockIdx.x;          // r = t*32 + b
  int b = r & 31, t = r >> 5;
  int k = threadIdx.x * 4;
  float4 c = *(const float4*)(chord + ((size_t)b * TT + t) * HIDDEN + k);
  float4 h = *(const float4*)(hfc + (size_t)b * HIDDEN + k);
  u32 p0 = pk2(h.x + c.x * 0.01f, h.y + c.y * 0.01f);
  u32 p1 = pk2(h.z + c.z * 0.01f, h.w + c.w * 0.01f);
  uint2 pv; pv.x = p0; pv.y = p1;
  *(uint2*)(x0 + (size_t)r * HIDDEN + k) = pv;
}

// ---------------- fp32 -> bf16 weight convert ----------------
__global__ __launch_bounds__(256) void cvt_kernel(const float* __restrict__ src,
                                                  short* __restrict__ dst, int n4) {
  int i = blockIdx.x * 256 + threadIdx.x;
  if (i < n4) {
    float4 v = ((const float4*)src)[i];
    uint2 pv; pv.x = pk2(v.x, v.y); pv.y = pk2(v.z, v.w);
    ((uint2*)dst)[i] = pv;
  }
}

// ---------------- GEMM: C[M][N] = A[M][K](bf16) @ Bw[N][K]^T(bf16), m97 recipe ----------------
template <typename OutT>
__global__ __launch_bounds__(256) void gemm_bt(const short* __restrict__ A,
                                               const short* __restrict__ Bw,
                                               OutT* __restrict__ C, int M, int N, int K) {
  __shared__ short As[128 * 32];
  __shared__ short Bs[128 * 32];
  const int tid = threadIdx.x;
  const int lane = tid & 63, wave = tid >> 6;
  const int l15 = lane & 15, quad = lane >> 4;
  const int n0 = blockIdx.x * 128, m0 = blockIdx.y * 128;
  const int wm = (wave >> 1) * 64, wn = (wave & 1) * 64;
  f32x4 acc[4][4] = {};
  for (int k0 = 0; k0 < K; k0 += 32) {
#pragma unroll
    for (int c = 0; c < 2; ++c) {
      int idx = c * 256 + tid;
      int row = idx >> 2, cs = (idx & 3) * 8;
      const u32* ga = (const u32*)(A + (size_t)(m0 + row) * K + k0 + cs);
      const u32* gb = (const u32*)(Bw + (size_t)(n0 + row) * K + k0 + cs);
      u32* sa = (u32*)As + (size_t)(c * 256 + wave * 64) * 4;
      u32* sb = (u32*)Bs + (size_t)(c * 256 + wave * 64) * 4;
      __builtin_amdgcn_global_load_lds(GLP(ga), LLP(sa), 16, 0, 0);
      __builtin_amdgcn_global_load_lds(GLP(gb), LLP(sb), 16, 0, 0);
    }
    __syncthreads();
    s16x8 af[4], bfr[4];
#pragma unroll
    for (int i = 0; i < 4; ++i)
      af[i] = *(const s16x8*)(As + (wm + i * 16 + l15) * 32 + quad * 8);
#pragma unroll
    for (int j = 0; j < 4; ++j)
      bfr[j] = *(const s16x8*)(Bs + (wn + j * 16 + l15) * 32 + quad * 8);
#pragma unroll
    for (int i = 0; i < 4; ++i)
#pragma unroll
      for (int j = 0; j < 4; ++j)
        acc[i][j] = __builtin_amdgcn_mfma_f32_16x16x32_bf16(af[i], bfr[j], acc[i][j], 0, 0, 0);
    __syncthreads();
  }
#pragma unroll
  for (int i = 0; i < 4; ++i)
#pragma unroll
    for (int j = 0; j < 4; ++j)
#pragma unroll
      for (int r = 0; r < 4; ++r) {
        int m = m0 + wm + i * 16 + quad * 4 + r;
        int n = n0 + wn + j * 16 + l15;
        float v = acc[i][j][r];
        if constexpr (__is_same(OutT, float)) C[(size_t)m * N + n] = v;
        else C[(size_t)m * N + n] = f2bf(v);
      }
}

// ---------------- persistent GRU layer ----------------
// 8 batch-groups x 16 WGs (32 hidden units each), 6 waves = gate x half.
// h exchange: tagged u64 words {tag | 2xbf16} via agent-scope relaxed atomics.
// No fences, no flags, no cache-maintenance ops. Double-buffered by t&1;
// tag = tag_base + t + 1 (layer-distinct tag_base -> no memset needed; 0xAA
// poison never matches a valid tag).
template <typename GxT>
__global__ __launch_bounds__(384) void gru_layer(const GxT* __restrict__ gx,       // [T][32][1536]
                                                 const float* __restrict__ w_hh,   // [1536][512]
                                                 const float* __restrict__ b_ih,
                                                 const float* __restrict__ b_hh,
                                                 u64* __restrict__ h_buf,          // [8][2][1024] u64
                                                 int tag_base,
                                                 short* __restrict__ x_out,        // [T][32][512] bf16 or null
                                                 float* __restrict__ f_out,        // [32][T][512] fp32 or null
                                                 const int* __restrict__ seq_lens) {
  const int bid = blockIdx.x;
  const int g = bid & 7, wg = bid >> 3;
  const int tid = threadIdx.x, lane = tid & 63, wave = tid >> 6;
  const int l15 = lane & 15, quad = lane >> 4;
  const int gate = wave >> 1, half = wave & 1;
  const int ub = wg * 32 + half * 16;
  const int col = gate * 512 + ub + l15;     // w_hh row this lane covers
  __shared__ u32 h_lds[1024];                // [4 rows][256 pairs]
  __shared__ float lds_gh[4][4][16];         // [(gate-1)*2+half][batch][unit]

  u64* hb = h_buf + (size_t)g * 2048;

  // --- persistent weight fragments (bf16, 64 VGPRs) ---
  s16x8 wfrag[16];
#pragma unroll
  for (int kb = 0; kb < 16; ++kb) {
    const float* p = w_hh + (size_t)col * 512 + kb * 32 + quad * 8;
    wfrag[kb] = f2bf8(*(const float4*)p, *(const float4*)(p + 4));
  }

  const int u = ub + l15;
  float bihr = 0, bihz = 0, bihn = 0, bhhr = 0, bhhz = 0, bhhn = 0;
  if (gate == 0) {
    bihr = b_ih[u]; bihz = b_ih[512 + u]; bihn = b_ih[1024 + u];
    bhhr = b_hh[u]; bhhz = b_hh[512 + u]; bhhn = b_hh[1024 + u];
  }
  int slen[4];
#pragma unroll
  for (int r = 0; r < 4; ++r) slen[r] = seq_lens[g * 4 + r];

  float hprev[4] = {0.f, 0.f, 0.f, 0.f};
  float pgx[3][4];
  if (gate == 0 && quad == 0) {
#pragma unroll
    for (int gt = 0; gt < 3; ++gt)
#pragma unroll
      for (int r = 0; r < 4; ++r)
        pgx[gt][r] = ldgx(&gx[(size_t)(g * 4 + r) * G3 + gt * 512 + u]);
  }

  const int w0 = tid, w1 = tid + 384, w2 = tid + 768;   // staging word slots

  for (int t = 0; t < TT; ++t) {
    // ---- stage h[t-1] into LDS: poll tagged words, no fences ----
    if (t > 0) {
      const u32 want = (u32)(tag_base + t);
      u64* src = hb + ((t - 1) & 1) * 1024;
      u64 v0 = __hip_atomic_load(src + w0, __ATOMIC_RELAXED, __HIP_MEMORY_SCOPE_AGENT);
      u64 v1 = __hip_atomic_load(src + w1, __ATOMIC_RELAXED, __HIP_MEMORY_SCOPE_AGENT);
      u64 v2 = (w2 < 1024)
                   ? __hip_atomic_load(src + w2, __ATOMIC_RELAXED, __HIP_MEMORY_SCOPE_AGENT)
                   : ((u64)want << 32);
      while ((u32)(v0 >> 32) != want)
        v0 = __hip_atomic_load(src + w0, __ATOMIC_RELAXED, __HIP_MEMORY_SCOPE_AGENT);
      while ((u32)(v1 >> 32) != want)
        v1 = __hip_atomic_load(src + w1, __ATOMIC_RELAXED, __HIP_MEMORY_SCOPE_AGENT);
      while ((u32)(v2 >> 32) != want)
        v2 = __hip_atomic_load(src + w2, __ATOMIC_RELAXED, __HIP_MEMORY_SCOPE_AGENT);
      h_lds[w0] = (u32)v0;
      h_lds[w1] = (u32)v1;
      if (w2 < 1024) h_lds[w2] = (u32)v2;
    }
    __syncthreads();

    float cur[3][4];
    if (gate == 0 && quad == 0) {
#pragma unroll
      for (int gt = 0; gt < 3; ++gt)
#pragma unroll
        for (int r = 0; r < 4; ++r) cur[gt][r] = pgx[gt][r];
      if (t + 1 < TT) {
#pragma unroll
        for (int gt = 0; gt < 3; ++gt)
#pragma unroll
          for (int r = 0; r < 4; ++r)
            pgx[gt][r] = ldgx(&gx[(size_t)((t + 1) * NB + g * 4 + r) * G3 + gt * 512 + u]);
      }
    }
    f32x4 acc = {0.f, 0.f, 0.f, 0.f};
    if (t > 0) {
      const u32* hrow = h_lds + (l15 & 3) * 256;
#pragma unroll
      for (int kb = 0; kb < 16; ++kb) {
        s16x8 a = *(const s16x8*)(hrow + kb * 16 + quad * 4);
        acc = __builtin_amdgcn_mfma_f32_16x16x32_bf16(a, wfrag[kb], acc, 0, 0, 0);
      }
    }
    if (gate > 0 && quad == 0) {
#pragma unroll
      for (int r = 0; r < 4; ++r) lds_gh[(gate - 1) * 2 + half][r][l15] = acc[r];
    }
    __syncthreads();
    if (gate == 0 && quad == 0) {
      const u64 tagv = ((u64)(u32)(tag_base + t + 1)) << 32;
      u64* dstb = hb + (t & 1) * 1024;
      float hv[4];
#pragma unroll
      for (int r = 0; r < 4; ++r) {
        float ghr = acc[r];
        float ghz = lds_gh[half][r][l15];
        float ghn = lds_gh[2 + half][r][l15];
        float xr = cur[0][r] + bihr + ghr + bhhr;
        float xz = cur[1][r] + bihz + ghz + bhhz;
        float rr = 1.f / (1.f + __expf(-xr));
        float zz = 1.f / (1.f + __expf(-xz));
        float pre = cur[2][r] + bihn + rr * (ghn + bhhn);
        float ax = fabsf(pre);
        float e = __expf(-2.f * ax);
        float nn = copysignf((1.f - e) / (1.f + e), pre);
        float h = (1.f - zz) * nn + zz * hprev[r];
        hprev[r] = h;
        hv[r] = h;
        float other = __shfl_xor(h, 1);
        if ((lane & 1) == 0) {
          u64 val = (u64)pk2(h, other) | tagv;
          __hip_atomic_store(dstb + r * 256 + (u >> 1), val,
                             __ATOMIC_RELAXED, __HIP_MEMORY_SCOPE_AGENT);
        }
      }
      // off-critical-path outputs after the tagged stores
#pragma unroll
      for (int r = 0; r < 4; ++r) {
        if (x_out) x_out[(size_t)(t * NB + g * 4 + r) * 512 + u] = f2bf(hv[r]);
        if (f_out) f_out[((size_t)(g * 4 + r) * TT + t) * 512 + u] = (t < slen[r]) ? hv[r] : 0.f;
      }
    }
  }
}

extern "C" void kernel_launch(void* const* d_in, const int* in_sizes, int n_in,
                              void* d_out, int out_size, void* d_ws, size_t ws_size,
                              hipStream_t stream) {
  (void)in_sizes; (void)n_in; (void)out_size;
  const float* z       = (const float*)d_in[0];
  const int*   seq     = (const int*)d_in[1];
  const float* chord   = (const float*)d_in[2];
  const float* fc_w    = (const float*)d_in[3];
  const float* fc_b    = (const float*)d_in[4];
  const float* w_ih[3] = {(const float*)d_in[5], (const float*)d_in[9],  (const float*)d_in[13]};
  const float* w_hh[3] = {(const float*)d_in[6], (const float*)d_in[10], (const float*)d_in[14]};
  const float* b_ih[3] = {(const float*)d_in[7], (const float*)d_in[11], (const float*)d_in[15]};
  const float* b_hh[3] = {(const float*)d_in[8], (const float*)d_in[12], (const float*)d_in[16]};

  char* w = (char*)d_ws;
  size_t off = 0;
  auto alloc = [&](size_t bytes) -> void* {
    void* p = w + off;
    off = (off + bytes + 255) & ~(size_t)255;
    return p;
  };
  u64*   hbuf = (u64*)alloc((size_t)8 * 2048 * 8);          // tagged h words
  float* hfc  = (float*)alloc((size_t)NB * HIDDEN * 4);
  short* x0   = (short*)alloc((size_t)TT * NB * HIDDEN * 2);
  short* x1   = (short*)alloc((size_t)TT * NB * GOUT * 2);   // reused as x2
  short* w0b  = (short*)alloc((size_t)G3 * HIDDEN * 2);
  short* w1b  = (short*)alloc((size_t)G3 * GOUT * 2);
  short* w2b  = (short*)alloc((size_t)G3 * GOUT * 2);
  size_t fixed = off;
  bool gx_f32 = (fixed + (size_t)TT * NB * G3 * 4) <= ws_size;
  void* gx = alloc(gx_f32 ? (size_t)TT * NB * G3 * 4 : (size_t)TT * NB * G3 * 2);

  fc_kernel<<<128, 256, 0, stream>>>(z, fc_w, fc_b, hfc);
  x0_kernel<<<TT * NB, 256, 0, stream>>>(hfc, chord, x0);
  cvt_kernel<<<(G3 * HIDDEN / 4 + 255) / 256, 256, 0, stream>>>(w_ih[0], w0b, G3 * HIDDEN / 4);
  cvt_kernel<<<(G3 * GOUT / 4 + 255) / 256, 256, 0, stream>>>(w_ih[1], w1b, G3 * GOUT / 4);
  cvt_kernel<<<(G3 * GOUT / 4 + 255) / 256, 256, 0, stream>>>(w_ih[2], w2b, G3 * GOUT / 4);

  dim3 gg(G3 / 128, TT * NB / 128);
  if (gx_f32) {
    float* gxf = (float*)gx;
    gemm_bt<float><<<gg, 256, 0, stream>>>(x0, w0b, gxf, TT * NB, G3, HIDDEN);
    gru_layer<float><<<128, 384, 0, stream>>>(gxf, w_hh[0], b_ih[0], b_hh[0], hbuf, 0 * 1024, x1, nullptr, seq);
    gemm_bt<float><<<gg, 256, 0, stream>>>(x1, w1b, gxf, TT * NB, G3, GOUT);
    gru_layer<float><<<128, 384, 0, stream>>>(gxf, w_hh[1], b_ih[1], b_hh[1], hbuf, 1 * 1024, x1, nullptr, seq);
    gemm_bt<float><<<gg, 256, 0, stream>>>(x1, w2b, gxf, TT * NB, G3, GOUT);
    gru_layer<float><<<128, 384, 0, stream>>>(gxf, w_hh[2], b_ih[2], b_hh[2], hbuf, 2 * 1024, nullptr, (float*)d_out, seq);
  } else {
    short* gxb = (short*)gx;
    gemm_bt<short><<<gg, 256, 0, stream>>>(x0, w0b, gxb, TT * NB, G3, HIDDEN);
    gru_layer<short><<<128, 384, 0, stream>>>(gxb, w_hh[0], b_ih[0], b_hh[0], hbuf, 0 * 1024, x1, nullptr, seq);
    gemm_bt<short><<<gg, 256, 0, stream>>>(x1, w1b, gxb, TT * NB, G3, GOUT);
    gru_layer<short><<<128, 384, 0, stream>>>(gxb, w_hh[1], b_ih[1], b_hh[1], hbuf, 1 * 1024, x1, nullptr, seq);
    gemm_bt<short><<<gg, 256, 0, stream>>>(x1, w2b, gxb, TT * NB, G3, GOUT);
    gru_layer<short><<<128, 384, 0, stream>>>(gxb, w_hh[2], b_ih[2], b_hh[2], hbuf, 2 * 1024, nullptr, (float*)d_out, seq);
  }
}